// Round 5
// baseline (193.776 us; speedup 1.0000x reference)
//
#include <hip/hip_runtime.h>

// Round 7 (resubmit #3 — infra failed three times: acquisition timeout,
// container failure, acquisition timeout; kernel never ran on HW).
// LDS-staged fd + finer buckets. Theory: edge kernel is bound by
// TA address serialization (~1 divergent lane-addr/cycle: 4M rows x 8 lanes
// / 256 CU = 52us ~= measured 54us; L2-residency only bought 13%, ILP 0%).
// Fix: bucket = (src>>7, dst-octile) -> ~3128 buckets; one block per bucket
// stages its 128 fd rows (16 KB) into LDS via COALESCED loads (TA fast
// path), serves fd from LDS (lgkm pipe, overlaps VMEM); only fg stays a
// divergent gather (still XCD-pinned L2-resident). Divergent lanes halve ->
// predict edge ~30us. Also fuse pack+bin into one dispatch (independent).
// Decision rule: edge >= 45us refutes the TA-lane model -> revert.

#define FD 64
#define MAX_BUCKETS 4096      // n_sb <= 512 (n_d < 65536) * 8 dst ranges
#define BIN_EPT 16
#define BIN_CHUNK (256 * BIN_EPT)   // 4096 edges per bin block

__device__ __forceinline__ int q8pack(float v0, float v1, float v2, float v3, float inv) {
    float a0 = fminf(fmaxf(v0 * inv, -127.f), 127.f);
    float a1 = fminf(fmaxf(v1 * inv, -127.f), 127.f);
    float a2 = fminf(fmaxf(v2 * inv, -127.f), 127.f);
    float a3 = fminf(fmaxf(v3 * inv, -127.f), 127.f);
    int q0 = ((int)rintf(a0)) & 0xff;
    int q1 = ((int)rintf(a1)) & 0xff;
    int q2 = ((int)rintf(a2)) & 0xff;
    int q3 = ((int)rintf(a3)) & 0xff;
    return q0 | (q1 << 8) | (q2 << 16) | (q3 << 24);
}

// Fused: blocks [0, nb_pack) do node packing; [nb_pack, nb_pack+nb_bin) do
// edge binning. Independent work -> overlap on the machine, one dispatch.
__global__ __launch_bounds__(256, 4)
void pack_bin_kernel(const float4* __restrict__ xd, const float4* __restrict__ hd,
                     const float4* __restrict__ xg, const float4* __restrict__ hg,
                     int2* __restrict__ fd, int2* __restrict__ fg,
                     float* __restrict__ sd, float* __restrict__ sg,
                     const int* __restrict__ src, const int* __restrict__ dst,
                     uint2* __restrict__ bins, unsigned* __restrict__ cursor,
                     int n_d, int n_g, int n_edges, int cap,
                     unsigned mul_d, int nb_pack)
{
    __shared__ unsigned hist[MAX_BUCKETS];
    __shared__ unsigned base[MAX_BUCKETS];

    int bid = (int)blockIdx.x;
    int t   = threadIdx.x;

    if (bid < nb_pack) {
        // ---------------- pack body ----------------
        int tid  = bid * 256 + t;
        int node = tid >> 4;
        int lane = t & 15;
        int total = n_d + n_g;
        if (node >= total) return;

        const float4* x; const float4* h; int2* o; float* s; int n;
        if (node < n_d) { x = xd; h = hd; o = fd; s = sd; n = node; }
        else            { x = xg; h = hg; o = fg; s = sg; n = node - n_d; }

        float4 a = x[(size_t)n * 16 + lane];
        float4 b = h[(size_t)n * 16 + lane];

        float ss = a.x*a.x + a.y*a.y + a.z*a.z + a.w*a.w
                 + b.x*b.x + b.y*b.y + b.z*b.z + b.w*b.w;
        #pragma unroll
        for (int m = 8; m >= 1; m >>= 1) ss += __shfl_xor(ss, m);
        float r = rsqrtf(ss);

        a.x *= r; a.y *= r; a.z *= r; a.w *= r;
        b.x *= r; b.y *= r; b.z *= r; b.w *= r;

        float mx = fmaxf(fmaxf(fmaxf(fabsf(a.x), fabsf(a.y)), fmaxf(fabsf(a.z), fabsf(a.w))),
                         fmaxf(fmaxf(fabsf(b.x), fabsf(b.y)), fmaxf(fabsf(b.z), fabsf(b.w))));
        #pragma unroll
        for (int m = 8; m >= 1; m >>= 1) mx = fmaxf(mx, __shfl_xor(mx, m));

        float inv = 127.0f / mx;

        int2 w;
        w.x = q8pack(a.x, a.y, a.z, a.w, inv);
        w.y = q8pack(b.x, b.y, b.z, b.w, inv);
        o[(size_t)n * 16 + lane] = w;

        if (lane == 0) s[n] = mx * (1.0f / 127.0f);
        return;
    }

    // ---------------- bin body ----------------
    int nbuck = ((n_d + 127) >> 7) * 8;
    for (int i = t; i < nbuck; i += 256) hist[i] = 0u;
    __syncthreads();

    int start = (bid - nb_pack) * BIN_CHUNK;
    unsigned pk[BIN_EPT]; unsigned bk[BIN_EPT];
    #pragma unroll
    for (int k = 0; k < BIN_EPT; ++k) {
        int e = start + t + k * 256;
        unsigned b = 0xffffffffu, p = 0u;
        if (e < n_edges) {
            unsigned s = (unsigned)src[e];
            unsigned d = (unsigned)dst[e];
            unsigned bd = min(7u, (d * mul_d) >> 20);
            b = (s >> 7) * 8u + bd;
            p = (s & 127u) | (d << 16);     // local src idx | dst
            atomicAdd(&hist[b], 1u);
        }
        pk[k] = p; bk[k] = b;
    }
    __syncthreads();
    for (int i = t; i < nbuck; i += 256) {
        unsigned h = hist[i];
        base[i] = h ? atomicAdd(&cursor[i], h) : 0u;
        hist[i] = 0u;                        // reuse as intra-block offset
    }
    __syncthreads();
    #pragma unroll
    for (int k = 0; k < BIN_EPT; ++k) {
        unsigned b = bk[k];
        if (b != 0xffffffffu) {
            unsigned r = atomicAdd(&hist[b], 1u);
            unsigned pos = base[b] + r;
            if (pos < (unsigned)cap)
                bins[(size_t)b * cap + pos] =
                    make_uint2(pk[k], (unsigned)(start + t + k * 256));
        }
    }
}

__device__ __forceinline__ int dot4(int a, int b, int c) {
    return __builtin_amdgcn_sdot4(a, b, c, false);   // v_dot4_i32_i8
}

// One block per bucket. Stage the bucket's 128 fd rows (16 KB) into LDS
// with coalesced loads + XOR swizzle (kills the all-rows-start-at-bank-0
// conflict), then loop the bucket's edges: fd from LDS, fg gathered from
// the XCD-pinned L2-resident dst slice. bucket id == blockIdx; b&7 = dst
// octile -> round-robin XCD pinning is automatic.
__global__ __launch_bounds__(256, 8)
void edge_kernel3(const int4* __restrict__ fd, const int4* __restrict__ fg,
                  const float* __restrict__ sd, const float* __restrict__ sg,
                  const uint2* __restrict__ bins, const unsigned* __restrict__ cursor,
                  float* __restrict__ out, int n_d, int cap)
{
    __shared__ int4 fdl[128 * 8];            // 128 rows x 128 B = 16 KB
    int b  = (int)blockIdx.x;                // bucket id
    int sb = b >> 3;
    int t  = threadIdx.x;
    int base_row = sb << 7;

    // coalesced stage: 1024 int4 slots, 256 threads x 4 iters
    for (int i = t; i < 1024; i += 256) {
        int r = i >> 3, l = i & 7;
        int gr = base_row + r;
        int4 v = make_int4(0, 0, 0, 0);
        if (gr < n_d) v = fd[(size_t)gr * 8 + l];
        fdl[(r << 3) | (l ^ (r & 7))] = v;   // swizzled slot
    }
    __syncthreads();

    int count = min((int)cursor[b], cap);
    int grp  = t >> 3;
    int lane = t & 7;
    const uint2* bb = bins + (size_t)b * cap;

    for (int e0 = grp * 2; e0 < count; e0 += 64) {
        bool has1 = (e0 + 1) < count;
        uint4 rr = ((const uint4*)bb)[e0 >> 1];   // cap even -> 16B aligned
        int s0 = (int)(rr.x & 127u),  d0 = (int)(rr.x >> 16);
        // odd-count tail: rr.z/w may be garbage; mask s1 into LDS bounds,
        // d1 stays inside d_ws (fg + 8.4MB < ws); output is guarded.
        int s1 = (int)(rr.z & 127u),  d1 = (int)(rr.z >> 16);

        int4 a0 = fdl[(s0 << 3) | (lane ^ (s0 & 7))];
        int4 a1 = fdl[(s1 << 3) | (lane ^ (s1 & 7))];
        int4 b0 = fg[(size_t)d0 * 8 + lane];
        int4 b1 = fg[(size_t)d1 * 8 + lane];

        int acc0 = dot4(a0.x, b0.x, dot4(a0.y, b0.y, dot4(a0.z, b0.z, dot4(a0.w, b0.w, 0))));
        int acc1 = dot4(a1.x, b1.x, dot4(a1.y, b1.y, dot4(a1.z, b1.z, dot4(a1.w, b1.w, 0))));

        acc0 += __shfl_xor(acc0, 4);
        acc0 += __shfl_xor(acc0, 2);
        acc0 += __shfl_xor(acc0, 1);
        acc1 += __shfl_xor(acc1, 4);
        acc1 += __shfl_xor(acc1, 2);
        acc1 += __shfl_xor(acc1, 1);

        if (lane == 0) {
            out[rr.y] = (float)acc0 * sd[base_row + s0] * sg[d0];
            if (has1) out[rr.w] = (float)acc1 * sd[base_row + s1] * sg[d1];
        }
    }
}

// Fallback (round-5 proven path) if ws can't hold bins or ids exceed 16 bit.
__global__ __launch_bounds__(256, 8)
void edge_kernel2(const int4* __restrict__ fd, const int4* __restrict__ fg,
                  const float* __restrict__ sd, const float* __restrict__ sg,
                  const int* __restrict__ src, const int* __restrict__ dst,
                  float* __restrict__ out, int n_edges)
{
    int tid  = (int)(blockIdx.x * blockDim.x + threadIdx.x);
    int lane = threadIdx.x & 7;
    int g    = tid >> 3;
    int e0   = g * 2;
    if (e0 >= n_edges) return;
    int  e1   = min(e0 + 1, n_edges - 1);
    bool has1 = (e0 + 1) < n_edges;

    int s0 = src[e0], d0 = dst[e0];
    int s1 = src[e1], d1 = dst[e1];

    int4 a0 = fd[(size_t)s0 * 8 + lane];
    int4 b0 = fg[(size_t)d0 * 8 + lane];
    int4 a1 = fd[(size_t)s1 * 8 + lane];
    int4 b1 = fg[(size_t)d1 * 8 + lane];

    int acc0 = dot4(a0.x, b0.x, dot4(a0.y, b0.y, dot4(a0.z, b0.z, dot4(a0.w, b0.w, 0))));
    int acc1 = dot4(a1.x, b1.x, dot4(a1.y, b1.y, dot4(a1.z, b1.z, dot4(a1.w, b1.w, 0))));

    acc0 += __shfl_xor(acc0, 4);
    acc0 += __shfl_xor(acc0, 2);
    acc0 += __shfl_xor(acc0, 1);
    acc1 += __shfl_xor(acc1, 4);
    acc1 += __shfl_xor(acc1, 2);
    acc1 += __shfl_xor(acc1, 1);

    if (lane == 0) {
        out[e0] = (float)acc0 * sd[s0] * sg[d0];
        if (has1) out[e1] = (float)acc1 * sd[s1] * sg[d1];
    }
}

extern "C" void kernel_launch(void* const* d_in, const int* in_sizes, int n_in,
                              void* d_out, int out_size, void* d_ws, size_t ws_size,
                              hipStream_t stream) {
    const float* xd = (const float*)d_in[0];
    const float* hd = (const float*)d_in[1];
    const float* xg = (const float*)d_in[2];
    const float* hg = (const float*)d_in[3];
    const int*  src = (const int*)d_in[4];
    const int*  dst = (const int*)d_in[5];

    int n_d     = in_sizes[0] / FD;
    int n_g     = in_sizes[2] / FD;
    int n_edges = in_sizes[4];

    int n_sb  = (n_d + 127) >> 7;
    int nbuck = n_sb * 8;

    // per-bucket capacity: mean + 12.5% + 96, rounded to 64 (even -> uint4 ok)
    int mean = (nbuck > 0) ? (n_edges / nbuck) : 0;
    int cap  = (mean + mean / 8 + 96 + 63) & ~63;

    size_t fd_b   = (size_t)n_d * 128;
    size_t fg_b   = (size_t)n_g * 128;
    size_t bins_b = (size_t)nbuck * (size_t)cap * sizeof(uint2);
    size_t need   = fd_b + fg_b + bins_b
                  + (size_t)(n_d + n_g) * sizeof(float)
                  + (size_t)nbuck * sizeof(unsigned) + 256;

    bool bucketed = (need <= ws_size) && (n_d < 65536) && (n_g < 65536)
                  && (nbuck <= MAX_BUCKETS) && (n_edges > 0);

    // ws layout: fd | fg | [bins] | sd | sg | [cursor]
    char* ws = (char*)d_ws;
    int2*  fd = (int2*)ws;  ws += fd_b;
    int2*  fg = (int2*)ws;  ws += fg_b;
    uint2* bins = nullptr;
    if (bucketed) { bins = (uint2*)ws; ws += bins_b; }
    float* sd = (float*)ws; ws += (size_t)n_d * sizeof(float);
    float* sg = (float*)ws; ws += (size_t)n_g * sizeof(float);
    unsigned* cursor = nullptr;
    if (bucketed) { cursor = (unsigned*)ws; }
    float* out = (float*)d_out;

    int total_nodes = n_d + n_g;
    int nb_pack = (total_nodes * 16 + 255) / 256;
    int nb_bin  = bucketed ? (n_edges + BIN_CHUNK - 1) / BIN_CHUNK : 0;

    unsigned mul_d = (n_g > 0) ? ((8u << 20) / (unsigned)n_g) : 0u;

    if (bucketed)
        hipMemsetAsync(cursor, 0, (size_t)nbuck * sizeof(unsigned), stream);

    pack_bin_kernel<<<nb_pack + nb_bin, 256, 0, stream>>>(
        (const float4*)xd, (const float4*)hd, (const float4*)xg, (const float4*)hg,
        fd, fg, sd, sg, src, dst, bins, cursor,
        n_d, n_g, n_edges, cap, mul_d, nb_pack);

    if (bucketed) {
        edge_kernel3<<<nbuck, 256, 0, stream>>>((const int4*)fd, (const int4*)fg,
                                                sd, sg, bins, cursor, out, n_d, cap);
    } else {
        long long groups = ((long long)n_edges + 1) / 2;
        int nb2 = (int)((groups * 8 + 255) / 256);
        edge_kernel2<<<nb2, 256, 0, stream>>>((const int4*)fd, (const int4*)fg,
                                              sd, sg, src, dst, out, n_edges);
    }
}

// Round 8
// 164.165 us; speedup vs baseline: 1.1804x; 1.1804x over previous
//
#include <hip/hip_runtime.h>

// Round 8 (resubmit #2 — GPUAcquisitionTimeout twice, never ran on HW):
// revert all binning (r6 64-bucket: -8us edge but +bin cost, net
// loss; r7 3128-bucket+LDS: pack_bin 60us, edge ~55 -> TA-lane model
// REFUTED by own decision rule). Edge-gather wall (~62us) is insensitive to
// L2 hit rate, lane count, and ILP -> last untested suspect is WORKGROUP
// LAUNCH RATE: r5 ran 31250 one-shot blocks (~1us lifetime each; ~122
// sequential block-waves/CU). Test: grid-stride persistent edge kernel
// (2048 blocks, ~15 pairs/group, 2-pair unroll = 8 gathers in flight),
// everything else identical to r5 (coalesced out, no bins).
// Also: pack slimmed to 8 lanes/node (half the waves, 6 shuffles vs 8).

#define FD 64
#define EDGE_BLOCKS 2048

__device__ __forceinline__ int q8pack(float v0, float v1, float v2, float v3, float inv) {
    float a0 = fminf(fmaxf(v0 * inv, -127.f), 127.f);
    float a1 = fminf(fmaxf(v1 * inv, -127.f), 127.f);
    float a2 = fminf(fmaxf(v2 * inv, -127.f), 127.f);
    float a3 = fminf(fmaxf(v3 * inv, -127.f), 127.f);
    int q0 = ((int)rintf(a0)) & 0xff;
    int q1 = ((int)rintf(a1)) & 0xff;
    int q2 = ((int)rintf(a2)) & 0xff;
    int q3 = ((int)rintf(a3)) & 0xff;
    return q0 | (q1 << 8) | (q2 << 16) | (q3 << 24);
}

// 8 lanes per node. Lane l holds dims [8l, 8l+8) of x (2 float4) and of h
// (2 float4); writes one int4 (16 int8) -> row = 8 lanes x 16 B = 128 B.
// Same layout for fd and fg, so the edge dot pairs identically.
__global__ __launch_bounds__(256, 8)
void pack_kernel(const float4* __restrict__ xd, const float4* __restrict__ hd,
                 const float4* __restrict__ xg, const float4* __restrict__ hg,
                 int4* __restrict__ fd, int4* __restrict__ fg,
                 float* __restrict__ sd, float* __restrict__ sg,
                 int n_d, int n_g)
{
    int tid  = (int)(blockIdx.x * blockDim.x + threadIdx.x);
    int node = tid >> 3;
    int lane = threadIdx.x & 7;
    int total = n_d + n_g;
    if (node >= total) return;

    const float4* x; const float4* h; int4* o; float* s; int n;
    if (node < n_d) { x = xd; h = hd; o = fd; s = sd; n = node; }
    else            { x = xg; h = hg; o = fg; s = sg; n = node - n_d; }

    float4 a0 = x[(size_t)n * 16 + lane * 2];
    float4 a1 = x[(size_t)n * 16 + lane * 2 + 1];
    float4 b0 = h[(size_t)n * 16 + lane * 2];
    float4 b1 = h[(size_t)n * 16 + lane * 2 + 1];

    float ss = a0.x*a0.x + a0.y*a0.y + a0.z*a0.z + a0.w*a0.w
             + a1.x*a1.x + a1.y*a1.y + a1.z*a1.z + a1.w*a1.w
             + b0.x*b0.x + b0.y*b0.y + b0.z*b0.z + b0.w*b0.w
             + b1.x*b1.x + b1.y*b1.y + b1.z*b1.z + b1.w*b1.w;
    #pragma unroll
    for (int m = 4; m >= 1; m >>= 1) ss += __shfl_xor(ss, m);
    float r = rsqrtf(ss);

    a0.x *= r; a0.y *= r; a0.z *= r; a0.w *= r;
    a1.x *= r; a1.y *= r; a1.z *= r; a1.w *= r;
    b0.x *= r; b0.y *= r; b0.z *= r; b0.w *= r;
    b1.x *= r; b1.y *= r; b1.z *= r; b1.w *= r;

    float mx = fmaxf(
        fmaxf(fmaxf(fmaxf(fabsf(a0.x), fabsf(a0.y)), fmaxf(fabsf(a0.z), fabsf(a0.w))),
              fmaxf(fmaxf(fabsf(a1.x), fabsf(a1.y)), fmaxf(fabsf(a1.z), fabsf(a1.w)))),
        fmaxf(fmaxf(fmaxf(fabsf(b0.x), fabsf(b0.y)), fmaxf(fabsf(b0.z), fabsf(b0.w))),
              fmaxf(fmaxf(fabsf(b1.x), fabsf(b1.y)), fmaxf(fabsf(b1.z), fabsf(b1.w)))));
    #pragma unroll
    for (int m = 4; m >= 1; m >>= 1) mx = fmaxf(mx, __shfl_xor(mx, m));

    float inv = 127.0f / mx;

    int4 w;
    w.x = q8pack(a0.x, a0.y, a0.z, a0.w, inv);
    w.y = q8pack(a1.x, a1.y, a1.z, a1.w, inv);
    w.z = q8pack(b0.x, b0.y, b0.z, b0.w, inv);
    w.w = q8pack(b1.x, b1.y, b1.z, b1.w, inv);
    o[(size_t)n * 8 + lane] = w;

    if (lane == 0) s[n] = mx * (1.0f / 127.0f);
}

__device__ __forceinline__ int dot4(int a, int b, int c) {
    return __builtin_amdgcn_sdot4(a, b, c, false);   // v_dot4_i32_i8
}

__device__ __forceinline__ void edge_pair(const int4* __restrict__ fd,
                                          const int4* __restrict__ fg,
                                          const float* __restrict__ sd,
                                          const float* __restrict__ sg,
                                          const int* __restrict__ src,
                                          const int* __restrict__ dst,
                                          float* __restrict__ out,
                                          int pair, int n_edges, int lane)
{
    int e0 = pair * 2;
    bool has1 = (e0 + 1) < n_edges;

    int s0, d0, s1, d1;
    if (has1) {
        int2 sp = ((const int2*)src)[pair];   // e0 even -> 8B aligned
        int2 dp = ((const int2*)dst)[pair];
        s0 = sp.x; s1 = sp.y; d0 = dp.x; d1 = dp.y;
    } else {
        s0 = src[e0]; d0 = dst[e0]; s1 = s0; d1 = d0;
    }

    int4 a0 = fd[(size_t)s0 * 8 + lane];
    int4 b0 = fg[(size_t)d0 * 8 + lane];
    int4 a1 = fd[(size_t)s1 * 8 + lane];
    int4 b1 = fg[(size_t)d1 * 8 + lane];

    int acc0 = dot4(a0.x, b0.x, dot4(a0.y, b0.y, dot4(a0.z, b0.z, dot4(a0.w, b0.w, 0))));
    int acc1 = dot4(a1.x, b1.x, dot4(a1.y, b1.y, dot4(a1.z, b1.z, dot4(a1.w, b1.w, 0))));

    acc0 += __shfl_xor(acc0, 4);
    acc0 += __shfl_xor(acc0, 2);
    acc0 += __shfl_xor(acc0, 1);
    acc1 += __shfl_xor(acc1, 4);
    acc1 += __shfl_xor(acc1, 2);
    acc1 += __shfl_xor(acc1, 1);

    if (lane == 0) {
        out[e0] = (float)acc0 * sd[s0] * sg[d0];
        if (has1) out[e0 + 1] = (float)acc1 * sd[s1] * sg[d1];
    }
}

// Grid-stride persistent edge kernel: EDGE_BLOCKS x 32 groups; each group
// walks pairs strided by total group count (out stays coalesced within a
// wave: 8 adjacent groups -> 16 consecutive edges -> 64 B store segment).
// 2-pair manual unroll -> 8 independent row gathers in flight.
__global__ __launch_bounds__(256, 8)
void edge_kernel4(const int4* __restrict__ fd, const int4* __restrict__ fg,
                  const float* __restrict__ sd, const float* __restrict__ sg,
                  const int* __restrict__ src, const int* __restrict__ dst,
                  float* __restrict__ out, int n_edges, int ngroups)
{
    int g    = (int)blockIdx.x * 32 + (threadIdx.x >> 3);
    int lane = threadIdx.x & 7;
    int npairs = (n_edges + 1) >> 1;

    int pair = g;
    for (; pair + ngroups < npairs; pair += 2 * ngroups) {
        edge_pair(fd, fg, sd, sg, src, dst, out, pair,           n_edges, lane);
        edge_pair(fd, fg, sd, sg, src, dst, out, pair + ngroups, n_edges, lane);
    }
    if (pair < npairs)
        edge_pair(fd, fg, sd, sg, src, dst, out, pair, n_edges, lane);
}

extern "C" void kernel_launch(void* const* d_in, const int* in_sizes, int n_in,
                              void* d_out, int out_size, void* d_ws, size_t ws_size,
                              hipStream_t stream) {
    const float* xd = (const float*)d_in[0];
    const float* hd = (const float*)d_in[1];
    const float* xg = (const float*)d_in[2];
    const float* hg = (const float*)d_in[3];
    const int*  src = (const int*)d_in[4];
    const int*  dst = (const int*)d_in[5];

    int n_d     = in_sizes[0] / FD;
    int n_g     = in_sizes[2] / FD;
    int n_edges = in_sizes[4];

    // ws layout: fd rows (n_d*128 B) | fg rows (n_g*128 B) | sd | sg
    char* ws = (char*)d_ws;
    int4*  fd = (int4*)ws;   ws += (size_t)n_d * 128;
    int4*  fg = (int4*)ws;   ws += (size_t)n_g * 128;
    float* sd = (float*)ws;  ws += (size_t)n_d * sizeof(float);
    float* sg = (float*)ws;
    float* out = (float*)d_out;

    int total_nodes = n_d + n_g;
    int nb1 = (total_nodes * 8 + 255) / 256;
    pack_kernel<<<nb1, 256, 0, stream>>>((const float4*)xd, (const float4*)hd,
                                         (const float4*)xg, (const float4*)hg,
                                         fd, fg, sd, sg, n_d, n_g);

    long long npairs = ((long long)n_edges + 1) / 2;
    int nb2 = (int)((npairs + 31) / 32);          // blocks if one pass
    if (nb2 > EDGE_BLOCKS) nb2 = EDGE_BLOCKS;     // persistent grid-stride
    if (nb2 < 1) nb2 = 1;
    int ngroups = nb2 * 32;
    edge_kernel4<<<nb2, 256, 0, stream>>>(fd, fg, sd, sg, src, dst,
                                          out, n_edges, ngroups);
}

// Round 11
// 158.399 us; speedup vs baseline: 1.2233x; 1.0364x over previous
//
#include <hip/hip_runtime.h>

// Round 9 (resubmit #2 — GPUAcquisitionTimeout twice, never ran on HW):
// cooperative index fetch. Launch-rate model refuted (r8 persistent
// grid: 65us vs r5 one-shot 62). Remaining untested address-rate redundancy:
// in r5/r8 the int2 src/dst index loads are issued by ALL 8 lanes of a group
// (8x redundant) = 128 of ~430 lane-addresses per wave-iteration. Fix: lanes
// 0-7 of each wave load the 8 groups' src-pairs, lanes 8-15 the dst-pairs
// (coalesced), distribute via __shfl (DS pipe, off the TA). Stores paired as
// float2. ~430 -> ~312 lane-addrs -> predict edge 62 -> ~45-50us.
// Decision rule: edge >= 58us kills the address-rate model too -> floor.
// Pack: r8's 8-lane form (proven passing; ~30us, layout shared with edge).

#define FD 64

__device__ __forceinline__ int q8pack(float v0, float v1, float v2, float v3, float inv) {
    float a0 = fminf(fmaxf(v0 * inv, -127.f), 127.f);
    float a1 = fminf(fmaxf(v1 * inv, -127.f), 127.f);
    float a2 = fminf(fmaxf(v2 * inv, -127.f), 127.f);
    float a3 = fminf(fmaxf(v3 * inv, -127.f), 127.f);
    int q0 = ((int)rintf(a0)) & 0xff;
    int q1 = ((int)rintf(a1)) & 0xff;
    int q2 = ((int)rintf(a2)) & 0xff;
    int q3 = ((int)rintf(a3)) & 0xff;
    return q0 | (q1 << 8) | (q2 << 16) | (q3 << 24);
}

// 8 lanes per node. Lane l holds dims [8l, 8l+8) of x (2 float4) and of h
// (2 float4); writes one int4 (16 int8) -> row = 8 lanes x 16 B = 128 B.
__global__ __launch_bounds__(256, 8)
void pack_kernel(const float4* __restrict__ xd, const float4* __restrict__ hd,
                 const float4* __restrict__ xg, const float4* __restrict__ hg,
                 int4* __restrict__ fd, int4* __restrict__ fg,
                 float* __restrict__ sd, float* __restrict__ sg,
                 int n_d, int n_g)
{
    int tid  = (int)(blockIdx.x * blockDim.x + threadIdx.x);
    int node = tid >> 3;
    int lane = threadIdx.x & 7;
    int total = n_d + n_g;
    if (node >= total) return;

    const float4* x; const float4* h; int4* o; float* s; int n;
    if (node < n_d) { x = xd; h = hd; o = fd; s = sd; n = node; }
    else            { x = xg; h = hg; o = fg; s = sg; n = node - n_d; }

    float4 a0 = x[(size_t)n * 16 + lane * 2];
    float4 a1 = x[(size_t)n * 16 + lane * 2 + 1];
    float4 b0 = h[(size_t)n * 16 + lane * 2];
    float4 b1 = h[(size_t)n * 16 + lane * 2 + 1];

    float ss = a0.x*a0.x + a0.y*a0.y + a0.z*a0.z + a0.w*a0.w
             + a1.x*a1.x + a1.y*a1.y + a1.z*a1.z + a1.w*a1.w
             + b0.x*b0.x + b0.y*b0.y + b0.z*b0.z + b0.w*b0.w
             + b1.x*b1.x + b1.y*b1.y + b1.z*b1.z + b1.w*b1.w;
    #pragma unroll
    for (int m = 4; m >= 1; m >>= 1) ss += __shfl_xor(ss, m);
    float r = rsqrtf(ss);

    a0.x *= r; a0.y *= r; a0.z *= r; a0.w *= r;
    a1.x *= r; a1.y *= r; a1.z *= r; a1.w *= r;
    b0.x *= r; b0.y *= r; b0.z *= r; b0.w *= r;
    b1.x *= r; b1.y *= r; b1.z *= r; b1.w *= r;

    float mx = fmaxf(
        fmaxf(fmaxf(fmaxf(fabsf(a0.x), fabsf(a0.y)), fmaxf(fabsf(a0.z), fabsf(a0.w))),
              fmaxf(fmaxf(fabsf(a1.x), fabsf(a1.y)), fmaxf(fabsf(a1.z), fabsf(a1.w)))),
        fmaxf(fmaxf(fmaxf(fabsf(b0.x), fabsf(b0.y)), fmaxf(fabsf(b0.z), fabsf(b0.w))),
              fmaxf(fmaxf(fabsf(b1.x), fabsf(b1.y)), fmaxf(fabsf(b1.z), fabsf(b1.w)))));
    #pragma unroll
    for (int m = 4; m >= 1; m >>= 1) mx = fmaxf(mx, __shfl_xor(mx, m));

    float inv = 127.0f / mx;

    int4 w;
    w.x = q8pack(a0.x, a0.y, a0.z, a0.w, inv);
    w.y = q8pack(a1.x, a1.y, a1.z, a1.w, inv);
    w.z = q8pack(b0.x, b0.y, b0.z, b0.w, inv);
    w.w = q8pack(b1.x, b1.y, b1.z, b1.w, inv);
    o[(size_t)n * 8 + lane] = w;

    if (lane == 0) s[n] = mx * (1.0f / 127.0f);
}

__device__ __forceinline__ int dot4(int a, int b, int c) {
    return __builtin_amdgcn_sdot4(a, b, c, false);   // v_dot4_i32_i8
}

// One-shot grid (r5 structure, launch rate proven non-factor). Wave = 8
// groups = 8 pairs = 16 edges. Cooperative idx fetch: lanes 0-7 load the
// wave's 8 src int2-pairs, lanes 8-15 the dst pairs (one coalesced exec-
// masked instruction each); __shfl distributes. Stores paired as float2.
__global__ __launch_bounds__(256, 8)
void edge_kernel5(const int4* __restrict__ fd, const int4* __restrict__ fg,
                  const float* __restrict__ sd, const float* __restrict__ sg,
                  const int* __restrict__ src, const int* __restrict__ dst,
                  float* __restrict__ out, int n_edges)
{
    int npairs = (n_edges + 1) >> 1;
    int wl   = threadIdx.x & 63;
    int wid  = threadIdx.x >> 6;                    // wave in block (0..3)
    int gw   = wl >> 3;                             // group in wave (0..7)
    int lane = wl & 7;
    int wavebase = (int)blockIdx.x * 32 + wid * 8;  // pair idx of group 0

    // cooperative index load (lanes 0..15 only)
    int2 r = make_int2(0, 0);
    if (wl < 16) {
        int pl = wavebase + (wl & 7);
        if (pl < npairs) {
            if ((n_edges & 1) && (pl == npairs - 1)) {
                // odd tail: int2 .y would read 4B past the array
                int v = (wl < 8) ? src[pl * 2] : dst[pl * 2];
                r = make_int2(v, v);
            } else {
                r = (wl < 8) ? ((const int2*)src)[pl]
                             : ((const int2*)dst)[pl];
            }
        }
    }

    int pair = wavebase + gw;
    if (pair >= npairs) return;                     // lanes 0-15 stay active
    int e0 = pair * 2;                              //   whenever any group is
    bool has1 = (e0 + 1) < n_edges;

    int s0 = __shfl(r.x, gw);
    int s1 = __shfl(r.y, gw);
    int d0 = __shfl(r.x, 8 + gw);
    int d1 = __shfl(r.y, 8 + gw);
    if (!has1) { s1 = s0; d1 = d0; }

    int4 a0 = fd[(size_t)s0 * 8 + lane];
    int4 b0 = fg[(size_t)d0 * 8 + lane];
    int4 a1 = fd[(size_t)s1 * 8 + lane];
    int4 b1 = fg[(size_t)d1 * 8 + lane];

    int acc0 = dot4(a0.x, b0.x, dot4(a0.y, b0.y, dot4(a0.z, b0.z, dot4(a0.w, b0.w, 0))));
    int acc1 = dot4(a1.x, b1.x, dot4(a1.y, b1.y, dot4(a1.z, b1.z, dot4(a1.w, b1.w, 0))));

    acc0 += __shfl_xor(acc0, 4);
    acc0 += __shfl_xor(acc0, 2);
    acc0 += __shfl_xor(acc0, 1);
    acc1 += __shfl_xor(acc1, 4);
    acc1 += __shfl_xor(acc1, 2);
    acc1 += __shfl_xor(acc1, 1);

    if (lane == 0) {
        float r0 = (float)acc0 * sd[s0] * sg[d0];
        if (has1) {
            float r1 = (float)acc1 * sd[s1] * sg[d1];
            ((float2*)out)[pair] = make_float2(r0, r1);   // e0 even -> aligned
        } else {
            out[e0] = r0;
        }
    }
}

extern "C" void kernel_launch(void* const* d_in, const int* in_sizes, int n_in,
                              void* d_out, int out_size, void* d_ws, size_t ws_size,
                              hipStream_t stream) {
    const float* xd = (const float*)d_in[0];
    const float* hd = (const float*)d_in[1];
    const float* xg = (const float*)d_in[2];
    const float* hg = (const float*)d_in[3];
    const int*  src = (const int*)d_in[4];
    const int*  dst = (const int*)d_in[5];

    int n_d     = in_sizes[0] / FD;
    int n_g     = in_sizes[2] / FD;
    int n_edges = in_sizes[4];

    // ws layout: fd rows (n_d*128 B) | fg rows (n_g*128 B) | sd | sg
    char* ws = (char*)d_ws;
    int4*  fd = (int4*)ws;   ws += (size_t)n_d * 128;
    int4*  fg = (int4*)ws;   ws += (size_t)n_g * 128;
    float* sd = (float*)ws;  ws += (size_t)n_d * sizeof(float);
    float* sg = (float*)ws;
    float* out = (float*)d_out;

    int total_nodes = n_d + n_g;
    int nb1 = (total_nodes * 8 + 255) / 256;
    pack_kernel<<<nb1, 256, 0, stream>>>((const float4*)xd, (const float4*)hd,
                                         (const float4*)xg, (const float4*)hg,
                                         fd, fg, sd, sg, n_d, n_g);

    int npairs = (n_edges + 1) / 2;
    int nb2 = (npairs + 31) / 32;
    if (nb2 < 1) nb2 = 1;
    edge_kernel5<<<nb2, 256, 0, stream>>>(fd, fg, sd, sg, src, dst,
                                          out, n_edges);
}